// Round 10
// baseline (275484.772 us; speedup 1.0000x reference)
//
#include <hip/hip_runtime.h>
#include <hip/hip_bf16.h>

// Problem constants (fixed by the reference)
#define B_  64
#define T_  128
#define E_  300
#define EP  320     // E padded to multiple of 32 for MFMA K-loop
#define H_  512
#define G4  2048    // 4*H
#define R_  128     // 2*B (s1+s2 batched; shared LSTM weights)
#define C_  256
#define M_  512
#define TS  (T_ + 1)  // h time slots: slot 0 = h0, slot t+1 = h(t)
#define NB  128     // recur blocks: 2 streams x 4 rowblocks x 16 jblocks
#define NE  8192    // embed blocks: 16 coltiles x 256 (r,t-half) x 2 dirs
#define SENT  0xFFFFFFFFFFFFFFFFULL  // 8B sentinel (4x bf16 NaN)
#define SENT4 0xFFFFFFFFu            // 4B sentinel (2x bf16 NaN)

typedef short bf16x8 __attribute__((ext_vector_type(8)));
typedef float f32x4  __attribute__((ext_vector_type(4)));
#define MFMA(a, b, c) __builtin_amdgcn_mfma_f32_16x16x32_bf16((a), (b), (c), 0, 0, 0)

__device__ __forceinline__ float fsig(float x) { return 1.0f / (1.0f + __expf(-x)); }
__device__ __forceinline__ float ftanh(float x) {
    float a = fminf(fabsf(x), 15.0f);
    float e = __expf(2.0f * a);
    return copysignf((e - 1.0f) / (e + 1.0f), x);
}
__device__ __forceinline__ ushort f2bf(float f) {
    __hip_bfloat16 h = __float2bfloat16(f);
    return *reinterpret_cast<ushort*>(&h);
}
__device__ __forceinline__ float bf2f(ushort u) {
    __hip_bfloat16 h = *reinterpret_cast<__hip_bfloat16*>(&u);
    return __bfloat162float(h);
}

// Shared-memory overlay: recur role and embed role never coexist in a block.
union __align__(16) SharedU {
    struct __align__(16) { ushort As[32][520]; float Gs[4][32][33]; } r;  // 50176 B
    struct __align__(16) { int toks[64]; ushort As[64][40]; ushort Bs[128][40]; } e;
};

// ---------------------------------------------------------------------------
// P0: f32 -> bf16 conversion for Wih/Whh/S1W (emb is converted inline in the
// embed role now). Region by blockIdx; K-padding zeros in [sk, dk).
// ---------------------------------------------------------------------------
__global__ __launch_bounds__(256) void k_cvt_all(
    const float* __restrict__ Wih_f, const float* __restrict__ Wih_b,
    const float* __restrict__ Whh_f, const float* __restrict__ Whh_b,
    const float* __restrict__ S1W,
    ushort* __restrict__ WihBf, ushort* __restrict__ WihBb,
    ushort* __restrict__ WhhBf, ushort* __restrict__ WhhBb,
    ushort* __restrict__ S1WB)
{
    int b = blockIdx.x;
    const float* src; ushort* dst; int r, sk, dk;
    if (b < 2048)      { src = Wih_f; dst = WihBf; r = b;        sk = E_;   dk = EP; }
    else if (b < 4096) { src = Wih_b; dst = WihBb; r = b - 2048; sk = E_;   dk = EP; }
    else if (b < 6144) { src = Whh_f; dst = WhhBf; r = b - 4096; sk = H_;   dk = H_; }
    else if (b < 8192) { src = Whh_b; dst = WhhBb; r = b - 6144; sk = H_;   dk = H_; }
    else               { src = S1W;   dst = S1WB;  r = b - 8192; sk = 2*H_; dk = 2*H_; }
    for (int c = threadIdx.x; c < dk; c += 256)
        dst[(long)r * dk + c] = (c < sk) ? f2bf(src[(long)r * sk + c]) : (ushort)0;
}

// P1: init h slot 0 (bf16) from the h0 inputs (after the 0xFF sentinel fill).
__global__ __launch_bounds__(256) void k_init(
    const float* __restrict__ s1_h0, const float* __restrict__ s2_h0,
    ushort* __restrict__ hfB, ushort* __restrict__ hbB)
{
    const int r = blockIdx.x;                    // 0..127
    const int rl = (r < B_) ? r : r - B_;
    const float* h0 = (r < B_) ? s1_h0 : s2_h0;  // [2][B][H]
    for (int j = threadIdx.x; j < H_; j += 256) {
        hfB[(long)r * TS * H_ + j] = f2bf(h0[(long)0 * B_ * H_ + (long)rl * H_ + j]);
        hbB[(long)r * TS * H_ + j] = f2bf(h0[(long)1 * B_ * H_ + (long)rl * H_ + j]);
    }
}

// ---------------------------------------------------------------------------
// K_FUSED: blockIdx < NB -> persistent LSTM recurrence (r9-validated dataflow);
//          blockIdx >= NB -> input-GEMM tile producing xW via 4B agent-atomic
//          stores (sentinel-cleared). Recur polls BOTH h(t) chunks and its
//          step-t xW chunks, so the input GEMM overlaps the recurrence instead
//          of running serially before it. xW layout: [dir][t][r][2048].
// Dead embed tiles (t0 >= len) store zeros immediately so recur never hangs.
// No deadlock: embed blocks are independent & retire; queued recur blocks
// dispatch as CUs free up; recur blocks are first in the grid anyway.
// ---------------------------------------------------------------------------
__global__ __launch_bounds__(256) void k_fused(
    const int* __restrict__ s1, const int* __restrict__ s2,
    const int* __restrict__ l1, const int* __restrict__ l2,
    const float* __restrict__ emb,
    const ushort* __restrict__ WihBf, const ushort* __restrict__ WihBb,
    const float* __restrict__ b_f, const float* __restrict__ b_b,
    ushort* __restrict__ xf, ushort* __restrict__ xb,
    ushort* __restrict__ hfB, ushort* __restrict__ hbB,
    const ushort* __restrict__ WhhBf, const ushort* __restrict__ WhhBb,
    const float* __restrict__ s1_c0, const float* __restrict__ s2_c0)
{
    __shared__ SharedU sh;
    const int tid = threadIdx.x;
    const int lane = tid & 63;

    if (blockIdx.x < NB) {
        // ================= RECUR ROLE (r9 structure + xW polling) ==========
        const int bx = blockIdx.x;
        const int s  = bx >> 6;          // stream: 0 fwd, 1 bwd
        const int rb = (bx >> 4) & 3;    // row block of 32
        const int jb = bx & 15;          // j block of 32
        const int r0 = rb * 32, j0 = jb * 32;

        const ushort* xW  = s ? xb : xf;
        const ushort* Whh = s ? WhhBb : WhhBf;
        ushort* hB = s ? hbB : hfB;

        const int g = tid >> 6;          // wave = gate (i,f,g,o)
        const int l15 = lane & 15, q8 = (lane >> 4) * 8;

        // Whh fragments resident in registers: wave g, 32 cols, K=512
        bf16x8 bfr[2][16];
#pragma unroll
        for (int nt = 0; nt < 2; ++nt) {
            const ushort* brow = &Whh[((long)g * H_ + j0 + nt * 16 + l15) * H_];
#pragma unroll
            for (int ks = 0; ks < 16; ++ks)
                bfr[nt][ks] = *(const bf16x8*)&brow[ks * 32 + q8];
        }

        // cell ownership: thread -> (row rr, 4 cols at jj)
        const int rr = tid >> 3, jj = (tid & 7) * 4;
        const int rg_ = r0 + rr;
        const int rl  = (rg_ < B_) ? rg_ : rg_ - B_;
        const float* c0p = (rg_ < B_) ? s1_c0 : s2_c0;   // [2][B][H]
        float cst[4];
#pragma unroll
        for (int cc = 0; cc < 4; ++cc)
            cst[cc] = c0p[(long)s * B_ * H_ + (long)rl * H_ + j0 + jj + cc];

        // A staging: thread -> (row arow, chunk aseg); swizzled chunk slot
        const int arow = tid >> 3, aseg = tid & 7;
        const int swz = ((aseg + arow) & 7) * 8;

        for (int t = 0; t < T_; ++t) {
            // poll h(t) chunks AND this step's xW chunks until non-sentinel
            const ushort* hrow = &hB[((long)(r0 + arow) * TS + t) * H_ + aseg * 8];
            const long xbase = ((long)t * R_ + rg_) * G4 + j0 + jj;
            unsigned long long hv[16];
            uint xv[8];
            bool ok;
            do {
#pragma unroll
                for (int i = 0; i < 16; ++i) {
                    const unsigned long long* p8 =
                        (const unsigned long long*)(hrow + (i >> 1) * 64 + (i & 1) * 4);
                    hv[i] = __hip_atomic_load(p8, __ATOMIC_RELAXED,
                                              __HIP_MEMORY_SCOPE_AGENT);
                }
#pragma unroll
                for (int g2 = 0; g2 < 4; ++g2) {
                    const uint* p4 = (const uint*)&xW[xbase + g2 * H_];
                    xv[g2 * 2 + 0] = __hip_atomic_load(p4 + 0, __ATOMIC_RELAXED,
                                                       __HIP_MEMORY_SCOPE_AGENT);
                    xv[g2 * 2 + 1] = __hip_atomic_load(p4 + 1, __ATOMIC_RELAXED,
                                                       __HIP_MEMORY_SCOPE_AGENT);
                }
                ok = true;
#pragma unroll
                for (int i = 0; i < 16; ++i) ok = ok && (hv[i] != SENT);
#pragma unroll
                for (int j2 = 0; j2 < 8; ++j2) ok = ok && (xv[j2] != SENT4);
                if (!ok) __builtin_amdgcn_s_sleep(1);
            } while (!ok);

#pragma unroll
            for (int sl = 0; sl < 8; ++sl) {
                uint4 av;
                av.x = (uint)hv[2 * sl];       av.y = (uint)(hv[2 * sl] >> 32);
                av.z = (uint)hv[2 * sl + 1];   av.w = (uint)(hv[2 * sl + 1] >> 32);
                *(uint4*)&sh.r.As[arow][sl * 64 + swz] = av;
            }
            __syncthreads();

            f32x4 acc[2][2] = {};   // [mtile][ntile]
#pragma unroll
            for (int ks = 0; ks < 16; ++ks) {
                const int e2 = ks * 32 + q8;
                const int sl = e2 >> 6;
                const int c  = (e2 >> 3) & 7;
                bf16x8 a0 = *(const bf16x8*)&sh.r.As[l15][sl * 64 + (((c + l15) & 7) << 3)];
                bf16x8 a1 = *(const bf16x8*)&sh.r.As[16 + l15][sl * 64 + (((c + l15) & 7) << 3)];
                acc[0][0] = MFMA(a0, bfr[0][ks], acc[0][0]);
                acc[0][1] = MFMA(a0, bfr[1][ks], acc[0][1]);
                acc[1][0] = MFMA(a1, bfr[0][ks], acc[1][0]);
                acc[1][1] = MFMA(a1, bfr[1][ks], acc[1][1]);
            }

            // publish gate pre-acts (C layout: col=lane&15, row=(lane>>4)*4+rg)
#pragma unroll
            for (int mt = 0; mt < 2; ++mt)
#pragma unroll
                for (int nt = 0; nt < 2; ++nt)
#pragma unroll
                    for (int rg2 = 0; rg2 < 4; ++rg2)
                        sh.r.Gs[g][mt * 16 + (lane >> 4) * 4 + rg2][nt * 16 + l15] =
                            acc[mt][nt][rg2];
            __syncthreads();

            // fused cell update for 4 cols
            ushort hp[4];
#pragma unroll
            for (int cc = 0; cc < 4; ++cc) {
                uint xv0 = (cc < 2) ? xv[0] : xv[1];
                uint xv1 = (cc < 2) ? xv[2] : xv[3];
                uint xv2 = (cc < 2) ? xv[4] : xv[5];
                uint xv3 = (cc < 2) ? xv[6] : xv[7];
                int shv = (cc & 1) * 16;
                float gi = sh.r.Gs[0][rr][jj + cc] + bf2f((ushort)(xv0 >> shv));
                float gf = sh.r.Gs[1][rr][jj + cc] + bf2f((ushort)(xv1 >> shv));
                float gg = sh.r.Gs[2][rr][jj + cc] + bf2f((ushort)(xv2 >> shv));
                float go = sh.r.Gs[3][rr][jj + cc] + bf2f((ushort)(xv3 >> shv));
                cst[cc] = fsig(gf) * cst[cc] + fsig(gi) * ftanh(gg);
                hp[cc] = f2bf(fsig(go) * ftanh(cst[cc]));
            }
            unsigned long long pk = (unsigned long long)hp[0]
                                  | ((unsigned long long)hp[1] << 16)
                                  | ((unsigned long long)hp[2] << 32)
                                  | ((unsigned long long)hp[3] << 48);
            __hip_atomic_store(
                (unsigned long long*)&hB[((long)rg_ * TS + t + 1) * H_ + j0 + jj],
                pk, __ATOMIC_RELAXED, __HIP_MEMORY_SCOPE_AGENT);
        }
    } else {
        // ================= EMBED ROLE (input GEMM -> xW, atomic stores) ====
        const int e = blockIdx.x - NB;
        const int nx  = e & 15;
        const int yy  = (e >> 4) & 255;
        const int dir = e >> 12;
        const int r   = yy >> 1;
        const int t0  = (yy & 1) * 64;
        const int N0  = nx * 128;
        const int L   = (r < B_) ? l1[r] : l2[r - B_];

        const int w = tid >> 6;
        const int wm = w & 1, wn = w >> 1;
        const int l15 = lane & 15, q8 = (lane >> 4) * 8;
        ushort* xout = dir ? xb : xf;
        const float* bias = dir ? b_b : b_f;

        if (L <= t0) {
            // dead tile: clear sentinels with zeros (values never used)
#pragma unroll
            for (int mt = 0; mt < 2; ++mt) {
                int tl = t0 + wm * 32 + mt * 16 + (lane >> 4) * 4;
#pragma unroll
                for (int nt = 0; nt < 4; ++nt) {
                    int col = N0 + wn * 64 + nt * 16 + l15;
#pragma unroll
                    for (int rg = 0; rg < 4; ++rg)
                        if (!(lane & 1))
                            __hip_atomic_store(
                                (uint*)&xout[((long)(tl + rg) * R_ + r) * G4 + col],
                                0u, __ATOMIC_RELAXED, __HIP_MEMORY_SCOPE_AGENT);
                }
            }
            return;
        }

        if (tid < 64) {
            int t  = t0 + tid;
            int tt = dir ? ((t < L) ? (L - 1 - t) : t) : t;
            sh.e.toks[tid] = (r < B_) ? s1[r * T_ + tt] : s2[(r - B_) * T_ + tt];
        }
        __syncthreads();

        const ushort* Wih = dir ? WihBb : WihBf;
        f32x4 acc[2][4] = {};

        for (int k0 = 0; k0 < EP; k0 += 32) {
            {   // A: gather f32 emb rows, convert to bf16 inline
                int row = tid >> 2, seg = tid & 3;
                int k = k0 + seg * 8;
                const float* erow = &emb[(long)sh.e.toks[row] * E_];
                ushort tmp[8];
                if (k + 8 <= E_) {
                    float4 f0 = *(const float4*)&erow[k];
                    float4 f1 = *(const float4*)&erow[k + 4];
                    tmp[0] = f2bf(f0.x); tmp[1] = f2bf(f0.y);
                    tmp[2] = f2bf(f0.z); tmp[3] = f2bf(f0.w);
                    tmp[4] = f2bf(f1.x); tmp[5] = f2bf(f1.y);
                    tmp[6] = f2bf(f1.z); tmp[7] = f2bf(f1.w);
                } else {
#pragma unroll
                    for (int i = 0; i < 8; ++i)
                        tmp[i] = (k + i < E_) ? f2bf(erow[k + i]) : (ushort)0;
                }
                *(uint4*)&sh.e.As[row][seg * 8] = *(uint4*)tmp;
            }
#pragma unroll
            for (int p = 0; p < 2; ++p) {   // B: 128 cols x 32 k (bf16, padded)
                int u = tid + p * 256;
                int row = u >> 2, seg = u & 3;
                *(uint4*)&sh.e.Bs[row][seg * 8] =
                    *(const uint4*)&Wih[(long)(N0 + row) * EP + k0 + seg * 8];
            }
            __syncthreads();
            bf16x8 af[2], bfr2[4];
#pragma unroll
            for (int mt = 0; mt < 2; ++mt)
                af[mt] = *(const bf16x8*)&sh.e.As[wm * 32 + mt * 16 + l15][q8];
#pragma unroll
            for (int nt = 0; nt < 4; ++nt)
                bfr2[nt] = *(const bf16x8*)&sh.e.Bs[wn * 64 + nt * 16 + l15][q8];
#pragma unroll
            for (int mt = 0; mt < 2; ++mt)
#pragma unroll
                for (int nt = 0; nt < 4; ++nt)
                    acc[mt][nt] = MFMA(af[mt], bfr2[nt], acc[mt][nt]);
            __syncthreads();
        }

        // store: pair adjacent cols via shfl_xor(1) -> 4B agent-atomic stores
#pragma unroll
        for (int mt = 0; mt < 2; ++mt) {
            int tl = t0 + wm * 32 + mt * 16 + (lane >> 4) * 4;
#pragma unroll
            for (int nt = 0; nt < 4; ++nt) {
                int col = N0 + wn * 64 + nt * 16 + l15;
                float bv = bias[col];
#pragma unroll
                for (int rg = 0; rg < 4; ++rg) {
                    uint v = f2bf(acc[mt][nt][rg] + bv);
                    uint pv = (uint)__shfl_xor((int)v, 1);
                    if (!(lane & 1))
                        __hip_atomic_store(
                            (uint*)&xout[((long)(tl + rg) * R_ + r) * G4 + col],
                            v | (pv << 16), __ATOMIC_RELAXED,
                            __HIP_MEMORY_SCOPE_AGENT);
                }
            }
        }
    }
}

// ---------------------------------------------------------------------------
// K3a: U[m,c] = tanh(Hout[m,:] @ S1W^T) via bf16 MFMA (unchanged).
// ---------------------------------------------------------------------------
__global__ __launch_bounds__(256) void k_attn_mfma(
    const ushort* __restrict__ hfB, const ushort* __restrict__ hbB,
    const int* __restrict__ l1, const int* __restrict__ l2,
    const ushort* __restrict__ S1WB, float* __restrict__ U)
{
    const int r  = blockIdx.y >> 1;
    const int t0 = (blockIdx.y & 1) * 64;
    const int N0 = blockIdx.x * 64;
    const int L  = (r < B_) ? l1[r] : l2[r - B_];
    if (L <= t0) return;

    const int tid = threadIdx.x;
    const int lane = tid & 63, w = tid >> 6;
    const int wm = w & 1, wn = w >> 1;
    const int l15 = lane & 15, q8 = (lane >> 4) * 8;

    __shared__ __align__(16) ushort As[64][72];
    __shared__ __align__(16) ushort Bs[64][72];

    f32x4 acc[2][2] = {};

    for (int k0 = 0; k0 < 2 * H_; k0 += 64) {
#pragma unroll
        for (int p = 0; p < 2; ++p) {   // A: 64 rows x 64 k
            int u = tid + p * 256;
            int row = u >> 3, seg = u & 7;
            int tpos = t0 + row;
            int k = k0 + seg * 8;
            long idx;
            const ushort* src;
            if (k0 < H_) {
                src = hfB; idx = ((long)r * TS + tpos + 1) * H_ + k;
            } else {
                int tt = (tpos < L) ? (L - 1 - tpos) : tpos;
                src = hbB; idx = ((long)r * TS + tt + 1) * H_ + (k - H_);
            }
            *(uint4*)&As[row][seg * 8] = *(const uint4*)&src[idx];
        }
#pragma unroll
        for (int p = 0; p < 2; ++p) {   // B: 64 cols x 64 k
            int u = tid + p * 256;
            int row = u >> 3, seg = u & 7;
            *(uint4*)&Bs[row][seg * 8] =
                *(const uint4*)&S1WB[(long)(N0 + row) * (2 * H_) + k0 + seg * 8];
        }
        __syncthreads();
#pragma unroll
        for (int ks = 0; ks < 2; ++ks) {
            bf16x8 a0 = *(const bf16x8*)&As[wm * 32 + l15][ks * 32 + q8];
            bf16x8 a1 = *(const bf16x8*)&As[wm * 32 + 16 + l15][ks * 32 + q8];
            bf16x8 b0 = *(const bf16x8*)&Bs[wn * 32 + l15][ks * 32 + q8];
            bf16x8 b1 = *(const bf16x8*)&Bs[wn * 32 + 16 + l15][ks * 32 + q8];
            acc[0][0] = MFMA(a0, b0, acc[0][0]);
            acc[0][1] = MFMA(a0, b1, acc[0][1]);
            acc[1][0] = MFMA(a1, b0, acc[1][0]);
            acc[1][1] = MFMA(a1, b1, acc[1][1]);
        }
        __syncthreads();
    }
#pragma unroll
    for (int mt = 0; mt < 2; ++mt) {
        int m = r * T_ + t0 + wm * 32 + mt * 16 + (lane >> 4) * 4;
#pragma unroll
        for (int nt = 0; nt < 2; ++nt) {
            int col = N0 + wn * 32 + nt * 16 + l15;
#pragma unroll
            for (int rg = 0; rg < 4; ++rg)
                U[(long)(m + rg) * C_ + col] = ftanh(acc[mt][nt][rg]);
        }
    }
}

// ---------------------------------------------------------------------------
// K3b: scores = U@S2W, masked softmax, pooled = attn @ Hout (unchanged).
// ---------------------------------------------------------------------------
__global__ __launch_bounds__(256) void k_attn_pool(
    const ushort* __restrict__ hfB, const ushort* __restrict__ hbB,
    const float* __restrict__ U, const float* __restrict__ S2W,
    const int* __restrict__ l1, const int* __restrict__ l2,
    float* __restrict__ pooled)
{
    const int r = blockIdx.x;
    const int L = (r < B_) ? l1[r] : l2[r - B_];
    const int tid = threadIdx.x;
    const int lane = tid & 63, w = tid >> 6;

    __shared__ float att[T_];

    for (int tt = w; tt < T_; tt += 4) {
        float p = 0.0f;
        if (tt < L) {
            const float* u = &U[(long)(r * T_ + tt) * C_];
            p = u[lane] * S2W[lane] + u[lane + 64] * S2W[lane + 64]
              + u[lane + 128] * S2W[lane + 128] + u[lane + 192] * S2W[lane + 192];
            for (int off = 32; off; off >>= 1) p += __shfl_down(p, off);
        }
        if (lane == 0) att[tt] = p;
    }
    __syncthreads();

    float mx = -1e30f;
    for (int tt = 0; tt < L; ++tt) mx = fmaxf(mx, att[tt]);
    __syncthreads();
    if (tid < T_) att[tid] = (tid < L) ? __expf(att[tid] - mx) : 0.0f;
    __syncthreads();
    float sum = 0.0f;
    for (int tt = 0; tt < L; ++tt) sum += att[tt];
    float inv = 1.0f / sum;

    for (int p = tid; p < 512; p += 256) {
        float a0 = 0.0f, a1 = 0.0f;
        if (p < 256) {
            int d = p * 2;
            for (int tt = 0; tt < L; ++tt) {
                uint hv = *(const uint*)&hfB[((long)r * TS + tt + 1) * H_ + d];
                a0 += att[tt] * bf2f((ushort)(hv & 0xffff));
                a1 += att[tt] * bf2f((ushort)(hv >> 16));
            }
            pooled[(long)r * (2 * H_) + d]     = a0 * inv;
            pooled[(long)r * (2 * H_) + d + 1] = a1 * inv;
        } else {
            int d = (p - 256) * 2;
            for (int tt = 0; tt < L; ++tt) {
                uint hv = *(const uint*)&hbB[((long)r * TS + (L - tt)) * H_ + d];
                a0 += att[tt] * bf2f((ushort)(hv & 0xffff));
                a1 += att[tt] * bf2f((ushort)(hv >> 16));
            }
            pooled[(long)r * (2 * H_) + H_ + d]     = a0 * inv;
            pooled[(long)r * (2 * H_) + H_ + d + 1] = a1 * inv;
        }
    }
}

// ---------------------------------------------------------------------------
// K4a: om[b][mm] = merged[b] . mlpW[mm] + mlpb[mm] (unchanged).
// ---------------------------------------------------------------------------
__global__ __launch_bounds__(256) void k_mlp1(
    const float* __restrict__ pooled,
    const float* __restrict__ mlpW, const float* __restrict__ mlpb,
    float* __restrict__ om)
{
    const int mg = blockIdx.x;      // 0..7
    const int b  = blockIdx.y;      // 0..63
    const int tid = threadIdx.x;
    const int lane = tid & 63, w = tid >> 6;

    __shared__ __align__(16) float sm[2048];

#pragma unroll
    for (int it = 0; it < 8; ++it) {
        int d = tid + it * 256;
        float v;
        if (d < 1024) {
            v = pooled[(long)b * 1024 + d] + pooled[(long)(B_ + b) * 1024 + d];
        } else {
            int dd = d - 1024;
            float x = pooled[(long)b * 1024 + dd] - pooled[(long)(B_ + b) * 1024 + dd];
            v = x * x;
        }
        sm[d] = v;
    }
    __syncthreads();

    for (int i = 0; i < 16; ++i) {
        int mm = mg * 64 + w * 16 + i;
        const float* wrow = &mlpW[(long)mm * 2048];
        float ax = 0.f, ay = 0.f, az = 0.f, aw = 0.f;
#pragma unroll
        for (int it = 0; it < 8; ++it) {
            int k = it * 256 + lane * 4;
            float4 wv = *(const float4*)&wrow[k];
            float4 sv = *(const float4*)&sm[k];
            ax += wv.x * sv.x; ay += wv.y * sv.y;
            az += wv.z * sv.z; aw += wv.w * sv.w;
        }
        float ssum = (ax + ay) + (az + aw);
        for (int off = 32; off; off >>= 1) ssum += __shfl_down(ssum, off);
        if (lane == 0) om[(long)b * M_ + mm] = ssum + mlpb[mm];
    }
}

// K4b: out[b] = sigmoid(om[b] . outW + outb)   (CLS = 1)
__global__ __launch_bounds__(256) void k_final(
    const float* __restrict__ om,
    const float* __restrict__ outW, const float* __restrict__ outb,
    float* __restrict__ out)
{
    const int b = blockIdx.x;
    const int tid = threadIdx.x;
    __shared__ float red[256];
    float p = om[(long)b * M_ + tid] * outW[tid]
            + om[(long)b * M_ + 256 + tid] * outW[256 + tid];
    red[tid] = p;
    __syncthreads();
    for (int off = 128; off > 0; off >>= 1) {
        if (tid < off) red[tid] += red[tid + off];
        __syncthreads();
    }
    if (tid == 0) out[b] = 1.0f / (1.0f + __expf(-(red[0] + outb[0])));
}

// ---------------------------------------------------------------------------
extern "C" void kernel_launch(void* const* d_in, const int* in_sizes, int n_in,
                              void* d_out, int out_size, void* d_ws, size_t ws_size,
                              hipStream_t stream)
{
    const int*   s1    = (const int*)d_in[0];
    const int*   s2    = (const int*)d_in[1];
    const int*   l1    = (const int*)d_in[2];
    const int*   l2    = (const int*)d_in[3];
    const float* s1_h0 = (const float*)d_in[4];
    const float* s1_c0 = (const float*)d_in[5];
    const float* s2_h0 = (const float*)d_in[6];
    const float* s2_c0 = (const float*)d_in[7];
    const float* emb   = (const float*)d_in[8];
    const float* Wih_f = (const float*)d_in[9];
    const float* Whh_f = (const float*)d_in[10];
    const float* b_f   = (const float*)d_in[11];
    const float* Wih_b = (const float*)d_in[12];
    const float* Whh_b = (const float*)d_in[13];
    const float* b_b   = (const float*)d_in[14];
    const float* S1W   = (const float*)d_in[15];
    const float* S2W   = (const float*)d_in[16];
    const float* mlpW  = (const float*)d_in[17];
    const float* mlpb  = (const float*)d_in[18];
    const float* outW  = (const float*)d_in[19];
    const float* outb  = (const float*)d_in[20];
    float* out = (float*)d_out;

    // Workspace carve (all 16B-aligned). xf/xb/hfB/hbB contiguous for the
    // single sentinel memset. xW layout: [t][r][2048] per direction.
    ushort* p16 = (ushort*)d_ws;
    ushort* WihBf = p16;  p16 += (long)G4 * EP;
    ushort* WihBb = p16;  p16 += (long)G4 * EP;
    ushort* WhhBf = p16;  p16 += (long)G4 * H_;
    ushort* WhhBb = p16;  p16 += (long)G4 * H_;
    ushort* S1WB  = p16;  p16 += (long)C_ * 2 * H_;
    ushort* xf    = p16;  p16 += (long)T_ * R_ * G4;
    ushort* xb    = p16;  p16 += (long)T_ * R_ * G4;
    ushort* hfB   = p16;  p16 += (long)R_ * TS * H_;
    ushort* hbB   = p16;  p16 += (long)R_ * TS * H_;
    float* pf = (float*)p16;
    float* U      = pf;   pf += (long)R_ * T_ * C_;
    float* pooled = pf;   pf += (long)R_ * 2 * H_;
    float* om     = pf;   pf += (long)B_ * M_;

    // sentinel-fill xW + h (one contiguous region, 0xFF = bf16 NaN patterns)
    size_t sentBytes = ((size_t)2 * T_ * R_ * G4 + (size_t)2 * R_ * TS * H_)
                       * sizeof(ushort);
    hipMemsetAsync(xf, 0xFF, sentBytes, stream);

    // P0/P1: weight conversion (emb handled inline in k_fused) + h0 init
    k_cvt_all<<<8448, 256, 0, stream>>>(Wih_f, Wih_b, Whh_f, Whh_b, S1W,
                                        WihBf, WihBb, WhhBf, WhhBb, S1WB);
    k_init<<<R_, 256, 0, stream>>>(s1_h0, s2_h0, hfB, hbB);

    // K_FUSED: recurrence (blocks 0..127) + input GEMM (blocks 128..8319)
    k_fused<<<NB + NE, 256, 0, stream>>>(
        s1, s2, l1, l2, emb, WihBf, WihBb, b_f, b_b,
        xf, xb, hfB, hbB, WhhBf, WhhBb, s1_c0, s2_c0);

    // K3: attention pooling
    k_attn_mfma<<<dim3(4, 256), 256, 0, stream>>>(hfB, hbB, l1, l2, S1WB, U);
    k_attn_pool<<<R_, 256, 0, stream>>>(hfB, hbB, U, S2W, l1, l2, pooled);

    // K4: MLP head
    k_mlp1<<<dim3(8, B_), 256, 0, stream>>>(pooled, mlpW, mlpb, om);
    k_final<<<B_, 256, 0, stream>>>(om, outW, outb, out);
}

// Round 11
// 799.205 us; speedup vs baseline: 344.6987x; 344.6987x over previous
//
#include <hip/hip_runtime.h>
#include <hip/hip_bf16.h>

// Problem constants (fixed by the reference)
#define B_  64
#define T_  128
#define E_  300
#define EP  320     // E padded to multiple of 32 for MFMA K-loop
#define H_  512
#define G4  2048    // 4*H
#define R_  128     // 2*B (s1+s2 batched; shared LSTM weights)
#define C_  256
#define M_  512
#define TS  (T_ + 1)  // h time slots: slot 0 = h0, slot t+1 = h(t)
#define NB  128     // persistent-kernel grid: 2 streams x 4 rowblocks x 16 jblocks
#define SENT 0xFFFFFFFFFFFFFFFFULL   // 4x bf16 NaN — unreachable by real h

typedef short bf16x8 __attribute__((ext_vector_type(8)));
typedef float f32x4  __attribute__((ext_vector_type(4)));
#define MFMA(a, b, c) __builtin_amdgcn_mfma_f32_16x16x32_bf16((a), (b), (c), 0, 0, 0)

__device__ __forceinline__ float fsig(float x) { return 1.0f / (1.0f + __expf(-x)); }
__device__ __forceinline__ float ftanh(float x) {
    float a = fminf(fabsf(x), 15.0f);
    float e = __expf(2.0f * a);
    return copysignf((e - 1.0f) / (e + 1.0f), x);
}
__device__ __forceinline__ ushort f2bf(float f) {
    __hip_bfloat16 h = __float2bfloat16(f);
    return *reinterpret_cast<ushort*>(&h);
}
__device__ __forceinline__ float bf2f(ushort u) {
    __hip_bfloat16 h = *reinterpret_cast<__hip_bfloat16*>(&u);
    return __bfloat162float(h);
}

// ---------------------------------------------------------------------------
// P0: fused f32 -> bf16 conversion for ALL weight tensors + h0/sentinel init.
// Blocks [0,40448): weight regions (K-padding zeros in [sk,dk)).
// Blocks [40448, 40576): h slot-0 init from h0 inputs (after 0xFF memset).
// ---------------------------------------------------------------------------
__global__ __launch_bounds__(256) void k_cvt_all(
    const float* __restrict__ emb,
    const float* __restrict__ Wih_f, const float* __restrict__ Wih_b,
    const float* __restrict__ Whh_f, const float* __restrict__ Whh_b,
    const float* __restrict__ S1W,
    const float* __restrict__ s1_h0, const float* __restrict__ s2_h0,
    ushort* __restrict__ embB,
    ushort* __restrict__ WihBf, ushort* __restrict__ WihBb,
    ushort* __restrict__ WhhBf, ushort* __restrict__ WhhBb,
    ushort* __restrict__ S1WB,
    ushort* __restrict__ hfB, ushort* __restrict__ hbB)
{
    int b = blockIdx.x;
    if (b >= 40448) {   // h0 init role
        const int r = b - 40448;                     // 0..127
        const int rl = (r < B_) ? r : r - B_;
        const float* h0 = (r < B_) ? s1_h0 : s2_h0;  // [2][B][H]
        for (int j = threadIdx.x; j < H_; j += 256) {
            hfB[(long)r * TS * H_ + j] = f2bf(h0[(long)0 * B_ * H_ + (long)rl * H_ + j]);
            hbB[(long)r * TS * H_ + j] = f2bf(h0[(long)1 * B_ * H_ + (long)rl * H_ + j]);
        }
        return;
    }
    const float* src; ushort* dst; int r, sk, dk;
    if (b < 32000)      { src = emb;   dst = embB;  r = b;          sk = E_;    dk = EP; }
    else if (b < 34048) { src = Wih_f; dst = WihBf; r = b - 32000;  sk = E_;    dk = EP; }
    else if (b < 36096) { src = Wih_b; dst = WihBb; r = b - 34048;  sk = E_;    dk = EP; }
    else if (b < 38144) { src = Whh_f; dst = WhhBf; r = b - 36096;  sk = H_;    dk = H_; }
    else if (b < 40192) { src = Whh_b; dst = WhhBb; r = b - 38144;  sk = H_;    dk = H_; }
    else                { src = S1W;   dst = S1WB;  r = b - 40192;  sk = 2*H_;  dk = 2*H_; }
    for (int c = threadIdx.x; c < dk; c += 256)
        dst[(long)r * dk + c] = (c < sk) ? f2bf(src[(long)r * sk + c]) : (ushort)0;
}

// ---------------------------------------------------------------------------
// K1: embedding gather + input GEMM via bf16 MFMA.
// Epilogue v2: adjacent-column pairing via shfl_xor(1) -> 4B stores (was 2B
// scalar stores; pairing logic HW-validated in round 10's embed role).
// ---------------------------------------------------------------------------
__global__ __launch_bounds__(256) void k_embed_mfma(
    const int* __restrict__ s1, const int* __restrict__ s2,
    const int* __restrict__ l1, const int* __restrict__ l2,
    const ushort* __restrict__ embB,
    const ushort* __restrict__ WihBf, const ushort* __restrict__ WihBb,
    const float* __restrict__ b_f, const float* __restrict__ b_b,
    ushort* __restrict__ xf, ushort* __restrict__ xb)
{
    const int dir = blockIdx.z;
    const int r   = blockIdx.y >> 1;
    const int t0  = (blockIdx.y & 1) * 64;
    const int N0  = blockIdx.x * 128;
    const int L   = (r < B_) ? l1[r] : l2[r - B_];
    if (L <= t0) return;

    const int tid = threadIdx.x;
    const int lane = tid & 63, w = tid >> 6;
    const int wm = w & 1, wn = w >> 1;
    const int l15 = lane & 15, q8 = (lane >> 4) * 8;

    __shared__ int toks[64];
    __shared__ __align__(16) ushort As[64][40];
    __shared__ __align__(16) ushort Bs[128][40];

    if (tid < 64) {
        int t  = t0 + tid;
        int tt = dir ? ((t < L) ? (L - 1 - t) : t) : t;
        toks[tid] = (r < B_) ? s1[r * T_ + tt] : s2[(r - B_) * T_ + tt];
    }
    __syncthreads();

    const ushort* Wih  = dir ? WihBb : WihBf;
    const float*  bias = dir ? b_b : b_f;

    f32x4 acc[2][4] = {};

    for (int k0 = 0; k0 < EP; k0 += 32) {
        {   // A: 64 rows x 32 k
            int row = tid >> 2, seg = tid & 3;
            *(uint4*)&As[row][seg * 8] =
                *(const uint4*)&embB[(long)toks[row] * EP + k0 + seg * 8];
        }
#pragma unroll
        for (int p = 0; p < 2; ++p) {   // B: 128 cols x 32 k
            int u = tid + p * 256;
            int row = u >> 2, seg = u & 3;
            *(uint4*)&Bs[row][seg * 8] =
                *(const uint4*)&Wih[(long)(N0 + row) * EP + k0 + seg * 8];
        }
        __syncthreads();
        bf16x8 af[2], bfr[4];
#pragma unroll
        for (int mt = 0; mt < 2; ++mt)
            af[mt] = *(const bf16x8*)&As[wm * 32 + mt * 16 + l15][q8];
#pragma unroll
        for (int nt = 0; nt < 4; ++nt)
            bfr[nt] = *(const bf16x8*)&Bs[wn * 64 + nt * 16 + l15][q8];
#pragma unroll
        for (int mt = 0; mt < 2; ++mt)
#pragma unroll
            for (int nt = 0; nt < 4; ++nt)
                acc[mt][nt] = MFMA(af[mt], bfr[nt], acc[mt][nt]);
        __syncthreads();
    }

    ushort* xout = dir ? xb : xf;
#pragma unroll
    for (int mt = 0; mt < 2; ++mt) {
        int m = r * T_ + t0 + wm * 32 + mt * 16 + (lane >> 4) * 4;
#pragma unroll
        for (int nt = 0; nt < 4; ++nt) {
            int col = N0 + wn * 64 + nt * 16 + l15;
            float bv = bias[col];
#pragma unroll
            for (int rg = 0; rg < 4; ++rg) {
                uint v = f2bf(acc[mt][nt][rg] + bv);
                uint pv = (uint)__shfl_xor((int)v, 1);
                if (!(lane & 1))
                    *(uint*)&xout[(long)(m + rg) * G4 + col] = v | (pv << 16);
            }
        }
    }
}

// ---------------------------------------------------------------------------
// K2 v8 (round-9 verbatim): PERSISTENT recurrence, DATAFLOW sync.
// h arrays pre-filled with 0xFF sentinels; each h chunk written exactly once
// (8B relaxed agent atomic store); consumers poll the chunks directly.
// Measured: 454 us (3.55 us/step) — the structural handoff floor (three
// independent sync schemes converged at 3.5-3.8 us/step).
// ---------------------------------------------------------------------------
__global__ __launch_bounds__(256) void k_recur(
    const ushort* __restrict__ xf, const ushort* __restrict__ xb,
    ushort* __restrict__ hfB, ushort* __restrict__ hbB,
    const ushort* __restrict__ WhhBf, const ushort* __restrict__ WhhBb,
    const float* __restrict__ s1_c0, const float* __restrict__ s2_c0)
{
    const int bx = blockIdx.x;
    const int s  = bx >> 6;          // stream: 0 fwd, 1 bwd
    const int rb = (bx >> 4) & 3;    // row block of 32
    const int jb = bx & 15;          // j block of 32
    const int r0 = rb * 32, j0 = jb * 32;

    const ushort* xW  = s ? xb : xf;
    const ushort* Whh = s ? WhhBb : WhhBf;
    ushort* hB = s ? hbB : hfB;

    const int tid = threadIdx.x;
    const int lane = tid & 63;
    const int g = tid >> 6;          // wave = gate (i,f,g,o)
    const int l15 = lane & 15, q8 = (lane >> 4) * 8;

    __shared__ __align__(16) ushort As[32][520];   // 32 rows x 512 k, swizzled chunks
    __shared__ float Gs[4][32][33];                // gate pre-acts 32 x 32

    // Whh fragments resident in registers: wave g, 32 cols (2 n-tiles), K=512
    bf16x8 bfr[2][16];
#pragma unroll
    for (int nt = 0; nt < 2; ++nt) {
        const ushort* brow = &Whh[((long)g * H_ + j0 + nt * 16 + l15) * H_];
#pragma unroll
        for (int ks = 0; ks < 16; ++ks)
            bfr[nt][ks] = *(const bf16x8*)&brow[ks * 32 + q8];
    }

    // cell ownership: thread -> (row rr, 4 cols at jj)
    const int rr = tid >> 3, jj = (tid & 7) * 4;
    const int rg_ = r0 + rr;
    const int rl  = (rg_ < B_) ? rg_ : rg_ - B_;
    const float* c0p = (rg_ < B_) ? s1_c0 : s2_c0;   // [2][B][H]
    float cst[4];
#pragma unroll
    for (int cc = 0; cc < 4; ++cc)
        cst[cc] = c0p[(long)s * B_ * H_ + (long)rl * H_ + j0 + jj + cc];

    // A staging: thread -> (row arow, chunk aseg); chunk placed at (aseg+arow)&7
    const int arow = tid >> 3, aseg = tid & 7;
    const int swz = ((aseg + arow) & 7) * 8;

    for (int t = 0; t < T_; ++t) {
        // xW gate pre-activations (4 cols x 4 gates) — issued before the
        // h poll so their latency hides under the wait
        uint2 xw[4];
        const long xbase = ((long)rg_ * T_ + t) * G4 + j0 + jj;
#pragma unroll
        for (int gg = 0; gg < 4; ++gg)
            xw[gg] = *(const uint2*)&xW[xbase + gg * H_];

        // h(t): poll the data itself. 16 x 8B chunks; reload all each pass.
        const ushort* hrow = &hB[((long)(r0 + arow) * TS + t) * H_ + aseg * 8];
        unsigned long long hv[16];
        bool ok;
        do {
#pragma unroll
            for (int i = 0; i < 16; ++i) {
                const unsigned long long* p8 =
                    (const unsigned long long*)(hrow + (i >> 1) * 64 + (i & 1) * 4);
                hv[i] = __hip_atomic_load(p8, __ATOMIC_RELAXED,
                                          __HIP_MEMORY_SCOPE_AGENT);
            }
            ok = true;
#pragma unroll
            for (int i = 0; i < 16; ++i)
                ok = ok && (hv[i] != SENT);
        } while (!ok);

#pragma unroll
        for (int sl = 0; sl < 8; ++sl) {
            uint4 av;
            av.x = (uint)hv[2 * sl];       av.y = (uint)(hv[2 * sl] >> 32);
            av.z = (uint)hv[2 * sl + 1];   av.w = (uint)(hv[2 * sl + 1] >> 32);
            *(uint4*)&As[arow][sl * 64 + swz] = av;
        }
        __syncthreads();

        f32x4 acc[2][2] = {};   // [mtile][ntile]
#pragma unroll
        for (int ks = 0; ks < 16; ++ks) {
            const int e  = ks * 32 + q8;
            const int sl = e >> 6;
            const int c  = (e >> 3) & 7;
            bf16x8 a0 = *(const bf16x8*)&As[l15][sl * 64 + (((c + l15) & 7) << 3)];
            bf16x8 a1 = *(const bf16x8*)&As[16 + l15][sl * 64 + (((c + l15) & 7) << 3)];
            acc[0][0] = MFMA(a0, bfr[0][ks], acc[0][0]);
            acc[0][1] = MFMA(a0, bfr[1][ks], acc[0][1]);
            acc[1][0] = MFMA(a1, bfr[0][ks], acc[1][0]);
            acc[1][1] = MFMA(a1, bfr[1][ks], acc[1][1]);
        }

        // publish gate pre-acts (C layout: col=lane&15, row=(lane>>4)*4+rg)
#pragma unroll
        for (int mt = 0; mt < 2; ++mt)
#pragma unroll
            for (int nt = 0; nt < 2; ++nt)
#pragma unroll
                for (int rg2 = 0; rg2 < 4; ++rg2)
                    Gs[g][mt * 16 + (lane >> 4) * 4 + rg2][nt * 16 + l15] =
                        acc[mt][nt][rg2];
        __syncthreads();

        // fused cell update for 4 cols
        ushort hp[4];
#pragma unroll
        for (int cc = 0; cc < 4; ++cc) {
            uint xv0 = (cc < 2) ? xw[0].x : xw[0].y;
            uint xv1 = (cc < 2) ? xw[1].x : xw[1].y;
            uint xv2 = (cc < 2) ? xw[2].x : xw[2].y;
            uint xv3 = (cc < 2) ? xw[3].x : xw[3].y;
            int sh = (cc & 1) * 16;
            float gi = Gs[0][rr][jj + cc] + bf2f((ushort)(xv0 >> sh));
            float gf = Gs[1][rr][jj + cc] + bf2f((ushort)(xv1 >> sh));
            float gg = Gs[2][rr][jj + cc] + bf2f((ushort)(xv2 >> sh));
            float go = Gs[3][rr][jj + cc] + bf2f((ushort)(xv3 >> sh));
            cst[cc] = fsig(gf) * cst[cc] + fsig(gi) * ftanh(gg);
            hp[cc] = f2bf(fsig(go) * ftanh(cst[cc]));
        }
        unsigned long long pk = (unsigned long long)hp[0]
                              | ((unsigned long long)hp[1] << 16)
                              | ((unsigned long long)hp[2] << 32)
                              | ((unsigned long long)hp[3] << 48);
        __hip_atomic_store(
            (unsigned long long*)&hB[((long)rg_ * TS + t + 1) * H_ + j0 + jj],
            pk, __ATOMIC_RELAXED, __HIP_MEMORY_SCOPE_AGENT);
    }
}

// ---------------------------------------------------------------------------
// K3a: U[m,c] = tanh(Hout[m,:] @ S1W^T) via bf16 MFMA (unchanged).
// ---------------------------------------------------------------------------
__global__ __launch_bounds__(256) void k_attn_mfma(
    const ushort* __restrict__ hfB, const ushort* __restrict__ hbB,
    const int* __restrict__ l1, const int* __restrict__ l2,
    const ushort* __restrict__ S1WB, float* __restrict__ U)
{
    const int r  = blockIdx.y >> 1;
    const int t0 = (blockIdx.y & 1) * 64;
    const int N0 = blockIdx.x * 64;
    const int L  = (r < B_) ? l1[r] : l2[r - B_];
    if (L <= t0) return;

    const int tid = threadIdx.x;
    const int lane = tid & 63, w = tid >> 6;
    const int wm = w & 1, wn = w >> 1;
    const int l15 = lane & 15, q8 = (lane >> 4) * 8;

    __shared__ __align__(16) ushort As[64][72];
    __shared__ __align__(16) ushort Bs[64][72];

    f32x4 acc[2][2] = {};

    for (int k0 = 0; k0 < 2 * H_; k0 += 64) {
#pragma unroll
        for (int p = 0; p < 2; ++p) {   // A: 64 rows x 64 k
            int u = tid + p * 256;
            int row = u >> 3, seg = u & 7;
            int tpos = t0 + row;
            int k = k0 + seg * 8;
            long idx;
            const ushort* src;
            if (k0 < H_) {
                src = hfB; idx = ((long)r * TS + tpos + 1) * H_ + k;
            } else {
                int tt = (tpos < L) ? (L - 1 - tpos) : tpos;
                src = hbB; idx = ((long)r * TS + tt + 1) * H_ + (k - H_);
            }
            *(uint4*)&As[row][seg * 8] = *(const uint4*)&src[idx];
        }
#pragma unroll
        for (int p = 0; p < 2; ++p) {   // B: 64 cols x 64 k
            int u = tid + p * 256;
            int row = u >> 3, seg = u & 7;
            *(uint4*)&Bs[row][seg * 8] =
                *(const uint4*)&S1WB[(long)(N0 + row) * (2 * H_) + k0 + seg * 8];
        }
        __syncthreads();
#pragma unroll
        for (int ks = 0; ks < 2; ++ks) {
            bf16x8 a0 = *(const bf16x8*)&As[wm * 32 + l15][ks * 32 + q8];
            bf16x8 a1 = *(const bf16x8*)&As[wm * 32 + 16 + l15][ks * 32 + q8];
            bf16x8 b0 = *(const bf16x8*)&Bs[wn * 32 + l15][ks * 32 + q8];
            bf16x8 b1 = *(const bf16x8*)&Bs[wn * 32 + 16 + l15][ks * 32 + q8];
            acc[0][0] = MFMA(a0, b0, acc[0][0]);
            acc[0][1] = MFMA(a0, b1, acc[0][1]);
            acc[1][0] = MFMA(a1, b0, acc[1][0]);
            acc[1][1] = MFMA(a1, b1, acc[1][1]);
        }
        __syncthreads();
    }
#pragma unroll
    for (int mt = 0; mt < 2; ++mt) {
        int m = r * T_ + t0 + wm * 32 + mt * 16 + (lane >> 4) * 4;
#pragma unroll
        for (int nt = 0; nt < 2; ++nt) {
            int col = N0 + wn * 32 + nt * 16 + l15;
#pragma unroll
            for (int rg = 0; rg < 4; ++rg)
                U[(long)(m + rg) * C_ + col] = ftanh(acc[mt][nt][rg]);
        }
    }
}

// ---------------------------------------------------------------------------
// K3b: scores = U@S2W, masked softmax, pooled = attn @ Hout (unchanged).
// ---------------------------------------------------------------------------
__global__ __launch_bounds__(256) void k_attn_pool(
    const ushort* __restrict__ hfB, const ushort* __restrict__ hbB,
    const float* __restrict__ U, const float* __restrict__ S2W,
    const int* __restrict__ l1, const int* __restrict__ l2,
    float* __restrict__ pooled)
{
    const int r = blockIdx.x;
    const int L = (r < B_) ? l1[r] : l2[r - B_];
    const int tid = threadIdx.x;
    const int lane = tid & 63, w = tid >> 6;

    __shared__ float att[T_];

    for (int tt = w; tt < T_; tt += 4) {
        float p = 0.0f;
        if (tt < L) {
            const float* u = &U[(long)(r * T_ + tt) * C_];
            p = u[lane] * S2W[lane] + u[lane + 64] * S2W[lane + 64]
              + u[lane + 128] * S2W[lane + 128] + u[lane + 192] * S2W[lane + 192];
            for (int off = 32; off; off >>= 1) p += __shfl_down(p, off);
        }
        if (lane == 0) att[tt] = p;
    }
    __syncthreads();

    float mx = -1e30f;
    for (int tt = 0; tt < L; ++tt) mx = fmaxf(mx, att[tt]);
    __syncthreads();
    if (tid < T_) att[tid] = (tid < L) ? __expf(att[tid] - mx) : 0.0f;
    __syncthreads();
    float sum = 0.0f;
    for (int tt = 0; tt < L; ++tt) sum += att[tt];
    float inv = 1.0f / sum;

    for (int p = tid; p < 512; p += 256) {
        float a0 = 0.0f, a1 = 0.0f;
        if (p < 256) {
            int d = p * 2;
            for (int tt = 0; tt < L; ++tt) {
                uint hv = *(const uint*)&hfB[((long)r * TS + tt + 1) * H_ + d];
                a0 += att[tt] * bf2f((ushort)(hv & 0xffff));
                a1 += att[tt] * bf2f((ushort)(hv >> 16));
            }
            pooled[(long)r * (2 * H_) + d]     = a0 * inv;
            pooled[(long)r * (2 * H_) + d + 1] = a1 * inv;
        } else {
            int d = (p - 256) * 2;
            for (int tt = 0; tt < L; ++tt) {
                uint hv = *(const uint*)&hbB[((long)r * TS + (L - tt)) * H_ + d];
                a0 += att[tt] * bf2f((ushort)(hv & 0xffff));
                a1 += att[tt] * bf2f((ushort)(hv >> 16));
            }
            pooled[(long)r * (2 * H_) + H_ + d]     = a0 * inv;
            pooled[(long)r * (2 * H_) + H_ + d + 1] = a1 * inv;
        }
    }
}

// ---------------------------------------------------------------------------
// K4a: om[b][mm] = merged[b] . mlpW[mm] + mlpb[mm] (unchanged).
// ---------------------------------------------------------------------------
__global__ __launch_bounds__(256) void k_mlp1(
    const float* __restrict__ pooled,
    const float* __restrict__ mlpW, const float* __restrict__ mlpb,
    float* __restrict__ om)
{
    const int mg = blockIdx.x;      // 0..7
    const int b  = blockIdx.y;      // 0..63
    const int tid = threadIdx.x;
    const int lane = tid & 63, w = tid >> 6;

    __shared__ __align__(16) float sm[2048];

#pragma unroll
    for (int it = 0; it < 8; ++it) {
        int d = tid + it * 256;
        float v;
        if (d < 1024) {
            v = pooled[(long)b * 1024 + d] + pooled[(long)(B_ + b) * 1024 + d];
        } else {
            int dd = d - 1024;
            float x = pooled[(long)b * 1024 + dd] - pooled[(long)(B_ + b) * 1024 + dd];
            v = x * x;
        }
        sm[d] = v;
    }
    __syncthreads();

    for (int i = 0; i < 16; ++i) {
        int mm = mg * 64 + w * 16 + i;
        const float* wrow = &mlpW[(long)mm * 2048];
        float ax = 0.f, ay = 0.f, az = 0.f, aw = 0.f;
#pragma unroll
        for (int it = 0; it < 8; ++it) {
            int k = it * 256 + lane * 4;
            float4 wv = *(const float4*)&wrow[k];
            float4 sv = *(const float4*)&sm[k];
            ax += wv.x * sv.x; ay += wv.y * sv.y;
            az += wv.z * sv.z; aw += wv.w * sv.w;
        }
        float ssum = (ax + ay) + (az + aw);
        for (int off = 32; off; off >>= 1) ssum += __shfl_down(ssum, off);
        if (lane == 0) om[(long)b * M_ + mm] = ssum + mlpb[mm];
    }
}

// K4b: out[b] = sigmoid(om[b] . outW + outb)   (CLS = 1)
__global__ __launch_bounds__(256) void k_final(
    const float* __restrict__ om,
    const float* __restrict__ outW, const float* __restrict__ outb,
    float* __restrict__ out)
{
    const int b = blockIdx.x;
    const int tid = threadIdx.x;
    __shared__ float red[256];
    float p = om[(long)b * M_ + tid] * outW[tid]
            + om[(long)b * M_ + 256 + tid] * outW[256 + tid];
    red[tid] = p;
    __syncthreads();
    for (int off = 128; off > 0; off >>= 1) {
        if (tid < off) red[tid] += red[tid + off];
        __syncthreads();
    }
    if (tid == 0) out[b] = 1.0f / (1.0f + __expf(-(red[0] + outb[0])));
}

// ---------------------------------------------------------------------------
extern "C" void kernel_launch(void* const* d_in, const int* in_sizes, int n_in,
                              void* d_out, int out_size, void* d_ws, size_t ws_size,
                              hipStream_t stream)
{
    const int*   s1    = (const int*)d_in[0];
    const int*   s2    = (const int*)d_in[1];
    const int*   l1    = (const int*)d_in[2];
    const int*   l2    = (const int*)d_in[3];
    const float* s1_h0 = (const float*)d_in[4];
    const float* s1_c0 = (const float*)d_in[5];
    const float* s2_h0 = (const float*)d_in[6];
    const float* s2_c0 = (const float*)d_in[7];
    const float* emb   = (const float*)d_in[8];
    const float* Wih_f = (const float*)d_in[9];
    const float* Whh_f = (const float*)d_in[10];
    const float* b_f   = (const float*)d_in[11];
    const float* Wih_b = (const float*)d_in[12];
    const float* Whh_b = (const float*)d_in[13];
    const float* b_b   = (const float*)d_in[14];
    const float* S1W   = (const float*)d_in[15];
    const float* S2W   = (const float*)d_in[16];
    const float* mlpW  = (const float*)d_in[17];
    const float* mlpb  = (const float*)d_in[18];
    const float* outW  = (const float*)d_in[19];
    const float* outb  = (const float*)d_in[20];
    float* out = (float*)d_out;

    // Workspace carve (all 16B-aligned)
    ushort* p16 = (ushort*)d_ws;
    ushort* embB  = p16;  p16 += (long)32000 * EP;
    ushort* WihBf = p16;  p16 += (long)G4 * EP;
    ushort* WihBb = p16;  p16 += (long)G4 * EP;
    ushort* WhhBf = p16;  p16 += (long)G4 * H_;
    ushort* WhhBb = p16;  p16 += (long)G4 * H_;
    ushort* S1WB  = p16;  p16 += (long)C_ * 2 * H_;
    ushort* xf    = p16;  p16 += (long)R_ * T_ * G4;
    ushort* xb    = p16;  p16 += (long)R_ * T_ * G4;
    ushort* hfB   = p16;  p16 += (long)R_ * TS * H_;
    ushort* hbB   = p16;  p16 += (long)R_ * TS * H_;
    float* pf = (float*)p16;
    float* U      = pf;   pf += (long)R_ * T_ * C_;
    float* pooled = pf;   pf += (long)R_ * 2 * H_;
    float* om     = pf;   pf += (long)B_ * M_;

    // sentinel-fill h arrays (0xFF bytes -> every 8B chunk = SENT); the
    // cvt_all init-role then writes real h0 into slot 0. hfB/hbB contiguous.
    hipMemsetAsync(hfB, 0xFF, (size_t)2 * R_ * TS * H_ * sizeof(ushort), stream);

    // P0: fused weight conversion + h0 init (one launch)
    k_cvt_all<<<40576, 256, 0, stream>>>(emb, Wih_f, Wih_b, Whh_f, Whh_b, S1W,
                                         s1_h0, s2_h0,
                                         embB, WihBf, WihBb, WhhBf, WhhBb, S1WB,
                                         hfB, hbB);

    // K1: input GEMM
    k_embed_mfma<<<dim3(16, 256, 2), 256, 0, stream>>>(
        s1, s2, l1, l2, embB, WihBf, WihBb, b_f, b_b, xf, xb);

    // K2: full recurrence in ONE persistent launch (dataflow sync)
    k_recur<<<NB, 256, 0, stream>>>(xf, xb, hfB, hbB, WhhBf, WhhBb,
                                    s1_c0, s2_c0);

    // K3: attention pooling
    k_attn_mfma<<<dim3(4, 256), 256, 0, stream>>>(hfB, hbB, l1, l2, S1WB, U);
    k_attn_pool<<<R_, 256, 0, stream>>>(hfB, hbB, U, S2W, l1, l2, pooled);

    // K4: MLP head
    k_mlp1<<<dim3(8, B_), 256, 0, stream>>>(pooled, mlpW, mlpb, om);
    k_final<<<B_, 256, 0, stream>>>(om, outW, outb, out);
}